// Round 4
// baseline (265.435 us; speedup 1.0000x reference)
//
#include <hip/hip_runtime.h>

// CRF loss (B=1024, T=512, L=62, K=64) for MI355X / gfx950.
// One 64-lane wave per batch (lane j = state j), 1024 blocks -> 1 wave/SIMD:
// runtime = straggler slen x per-step DEPENDENT LATENCY (no TLP exists).
// Linear-domain recursion q_j <- W_j * sum_i q_i E_ij, E = exp(trans).
//
// R2/R3 change: NO LDS in the loop. rocprof R2 showed 530 cy/step with
// VALUBusy 17% -> 83% of time was LDS write->read round-trip latency.
// Replaced with an all-VALU hierarchical scheme:
//   1) DPP gather within the 16-lane row: quad_perm xor1/xor2, row_ror(4/12)
//      select for the +-4 stage, row_ror:8 for xor8 -> each lane holds its
//      16-block of h (8 packed h2 regs).
//   2) 4 partial dots per lane over its 16 rows, for columns
//      {me, me^16, me^32, me^48} (32 fdot2, 4 indep f32 accumulators).
//   3) Merge across 16/32 boundaries with v_permlane16_swap_b32 /
//      v_permlane32_swap_b32 (inline asm, gfx950-new; NOT the builtin --
//      its return-type signature varies across ROCm versions):
//      ss = (pA + X16(pB)) + X32(pC + X16(pD)).
// Direction/orientation of DPP rotates and permlane swaps is PROBED at init
// by running the identical network on lane-ID payloads; Eh row order and
// partner columns are loaded per the probe -> correct for any consistent HW
// permutation. psum (init) reuses the same merge with h==1.
// E rows 62/63 are exactly 0 (trans=-10000 -> exp underflow), so junk h on
// lanes 62/63 never leaks into columns < 62, and all 8 pairs dot safely.
// Same-step exponent renorm (exact 2^-(ex+6), integer accumulator Ci) --
// numerically identical to the verified 261.8us LDS kernel.
// First step analytic (uniform SMALL -> c_base); final step in log domain.
// Gold path score fused; one atomicAdd(ln2*logZ2 - gold) per block.

#define SMALLF   (-1000.0f)
#define LOG2E_F  1.4426950408889634f
#define LN2_F    0.6931471805599453f

#if defined(__has_builtin)
#if __has_builtin(__builtin_amdgcn_exp2f)
#define EXP2F(x) __builtin_amdgcn_exp2f(x)
#else
#define EXP2F(x) exp2f(x)
#endif
#if __has_builtin(__builtin_amdgcn_logf)
#define LOG2F(x) __builtin_amdgcn_logf(x)
#else
#define LOG2F(x) log2f(x)
#endif
#else
#define EXP2F(x) exp2f(x)
#define LOG2F(x) log2f(x)
#endif

typedef _Float16 h2 __attribute__((ext_vector_type(2)));

#if defined(__has_builtin) && __has_builtin(__builtin_amdgcn_fdot2)
#define FDOT2(a, b, c) __builtin_amdgcn_fdot2((a), (b), (c), false)
#else
#define FDOT2(a, b, c) fmaf((float)(a).x, (float)(b).x, \
                            fmaf((float)(a).y, (float)(b).y, (c)))
#endif

// DPP move: dst[lane] = src[perm(lane)], full masks, all lanes active.
template <int CTRL>
__device__ __forceinline__ unsigned dppmov(unsigned v) {
    return (unsigned)__builtin_amdgcn_update_dpp((int)v, (int)v, CTRL, 0xF, 0xF, false);
}
#define DPP_QP_X1 0xB1   // quad_perm [1,0,3,2] = xor 1
#define DPP_QP_X2 0x4E   // quad_perm [2,3,0,1] = xor 2
#define DPP_ROR4  0x124
#define DPP_ROR8  0x128  // within-16 rotate by 8 = xor 8 (direction-proof)
#define DPP_ROR12 0x12C

// +-4 stage within the 16-row: pick ror4 or ror12 per lane bit2. Whatever the
// HW rotate direction, the result is a fixed bijective permutation (covers
// the remaining two quads either way) and is covered by the probe.
__device__ __forceinline__ unsigned x4sel(unsigned v, bool b2) {
    const unsigned a = dppmov<DPP_ROR4>(v);
    const unsigned b = dppmov<DPP_ROR12>(v);
    return b2 ? a : b;
}

// 16-boundary exchange: v_permlane16_swap_b32 with both operands = v yields
// {r0,r0,r2,r2} in one output and {r1,r1,r3,r3} in the other (16-lane rows);
// per-lane select (row parity ^ probed flip) realizes lane <-> lane^16.
__device__ __forceinline__ unsigned x16(unsigned v, bool sel) {
    unsigned a = v, b = v;
    asm("v_permlane16_swap_b32 %0, %1" : "+v"(a), "+v"(b));
    return sel ? a : b;
}
// 32-boundary exchange, same construction with v_permlane32_swap_b32.
__device__ __forceinline__ unsigned x32(unsigned v, bool sel) {
    unsigned a = v, b = v;
    asm("v_permlane32_swap_b32 %0, %1" : "+v"(a), "+v"(b));
    return sel ? a : b;
}

__device__ __forceinline__ float bcast_first(float v) {
    return __uint_as_float(__builtin_amdgcn_readfirstlane(__float_as_uint(v)));
}

// wave-uniform scale 2^-(ex+6) from ss_lane0; accumulates ex+6 into Ci.
__device__ __forceinline__ float step_scale(float ss, int& Ci) {
    const float s0 = bcast_first(ss);
    const int ex = (int)((__float_as_uint(s0) >> 23) & 0xFF) - 127;  // s0>0 normal
    Ci += ex + 6;
    return __uint_as_float((unsigned)(127 - ex - 6) << 23);          // exact 2^-(ex+6)
}

// One recursion dot: per-lane h (f32) -> ss[lane] = sum_i h_i E[i][lane].
// All-register: DPP gather-16, 4 partial dots, permlane merges.
__device__ __forceinline__ float step_ss(float hf,
                                         const h2* __restrict__ EhA,
                                         const h2* __restrict__ EhB,
                                         const h2* __restrict__ EhC,
                                         const h2* __restrict__ EhD,
                                         bool b2, bool s16, bool s32) {
    const unsigned n1 = dppmov<DPP_QP_X1>(__float_as_uint(hf));
    unsigned r[8];
    r[0] = __builtin_bit_cast(unsigned,
              __builtin_amdgcn_cvt_pkrtz(hf, __uint_as_float(n1)));
    r[1] = dppmov<DPP_QP_X2>(r[0]);
    r[2] = x4sel(r[0], b2);
    r[3] = x4sel(r[1], b2);
    r[4] = dppmov<DPP_ROR8>(r[0]);
    r[5] = dppmov<DPP_ROR8>(r[1]);
    r[6] = dppmov<DPP_ROR8>(r[2]);
    r[7] = dppmov<DPP_ROR8>(r[3]);
    float pA = 0.f, pB = 0.f, pC = 0.f, pD = 0.f;
#pragma unroll
    for (int k = 0; k < 8; ++k) {
        const h2 v = __builtin_bit_cast(h2, r[k]);
        pA = FDOT2(v, EhA[k], pA);
        pB = FDOT2(v, EhB[k], pB);
        pC = FDOT2(v, EhC[k], pC);
        pD = FDOT2(v, EhD[k], pD);
    }
    const float A  = pA + __uint_as_float(x16(__float_as_uint(pB), s16));
    const float A2 = pC + __uint_as_float(x16(__float_as_uint(pD), s16));
    return A + __uint_as_float(x32(__float_as_uint(A2), s32));
}

__global__ __launch_bounds__(64, 1) void crf_fused_kernel(
    const float* __restrict__ pred,     // (B,T,L)
    const int*   __restrict__ ref,      // (B,T)
    const int*   __restrict__ seq_len,  // (B,)
    const float* __restrict__ trans,    // (64,64)
    float*       __restrict__ out,      // scalar, pre-zeroed
    int T, int L)
{
    const int b    = blockIdx.x;
    const unsigned lane = threadIdx.x;
    const int slen = seq_len[b];
    const int nmid = slen - 1;              // middle steps t = 2..slen
    const float* prow = pred + (size_t)b * T * L;
    const int*   rrow = ref  + (size_t)b * T;
    const bool mine = (lane < 62);

    // ---- gold score, two-phase gather (indices first, then values)
    int cidx[8], pidx[8];
#pragma unroll
    for (int k = 0; k < 8; ++k) {
        const int t = (int)lane + (k << 6);
        cidx[k] = (t < slen) ? rrow[t] : 0;
        pidx[k] = (t >= 1 && t < slen) ? rrow[t - 1] : 0;
    }
    float gacc = 0.f;
#pragma unroll
    for (int k = 0; k < 8; ++k) {
        const int t = (int)lane + (k << 6);
        if (t < slen) {
            gacc += prow[(size_t)t * L + cidx[k]];
            if (t >= 1) gacc += trans[(pidx[k] << 6) + cidx[k]];
        }
    }
    if (lane == 0)
        gacc += trans[(62 << 6) + rrow[0]] + trans[(rrow[slen - 1] << 6) + 63];

    // ---- probe the exchange network (payload = lane id) ------------------
    const bool b2 = (lane & 4u) != 0;
    bool flip16 = false, flip32 = false;
    {
        const unsigned p = x16(lane, ((lane >> 4) & 1u) != 0);
        if (__builtin_amdgcn_readfirstlane((int)p) == 0) flip16 = true;  // identity -> flip
        const unsigned q = x32(lane, ((lane >> 5) & 1u) != 0);
        if (__builtin_amdgcn_readfirstlane((int)q) == 0) flip32 = true;
    }
    const bool s16 = ((((lane >> 4) & 1u) != 0) != flip16);
    const bool s32 = ((((lane >> 5) & 1u) != 0) != flip32);
    const unsigned m16 = x16(lane, s16);        // my 16-exchange partner
    const unsigned m32 = x32(lane, s32);        // my 32-exchange partner
    const unsigned cD  = x16(m32, s16);         // = 32-partner of my 16-partner

    // probe the gather: packed two lane-ids per reg, same ops as step_ss
    unsigned gp[8];
    gp[0] = lane | (dppmov<DPP_QP_X1>(lane) << 16);
    gp[1] = dppmov<DPP_QP_X2>(gp[0]);
    gp[2] = x4sel(gp[0], b2);
    gp[3] = x4sel(gp[1], b2);
    gp[4] = dppmov<DPP_ROR8>(gp[0]);
    gp[5] = dppmov<DPP_ROR8>(gp[1]);
    gp[6] = dppmov<DPP_ROR8>(gp[2]);
    gp[7] = dppmov<DPP_ROR8>(gp[3]);

    // ---- E fragments per probed row order, 4 column sets -----------------
    // EhA: col = lane; EhB: col = m16; EhC: col = m32; EhD: col = cD.
    h2 EhA[8], EhB[8], EhC[8], EhD[8];
    float sA = 0.f, sB = 0.f, sC = 0.f, sD = 0.f;   // partial col-sums for psum
#pragma unroll
    for (int k = 0; k < 8; ++k) {
        const unsigned rlo = gp[k] & 0xFFFFu;
        const unsigned rhi = gp[k] >> 16;
        const float a0 = EXP2F(trans[rlo * 64u + lane] * LOG2E_F);
        const float a1 = EXP2F(trans[rhi * 64u + lane] * LOG2E_F);
        EhA[k].x = (_Float16)a0; EhA[k].y = (_Float16)a1; sA += a0 + a1;
        const float b0 = EXP2F(trans[rlo * 64u + m16] * LOG2E_F);
        const float b1 = EXP2F(trans[rhi * 64u + m16] * LOG2E_F);
        EhB[k].x = (_Float16)b0; EhB[k].y = (_Float16)b1; sB += b0 + b1;
        const float c0 = EXP2F(trans[rlo * 64u + m32] * LOG2E_F);
        const float c1 = EXP2F(trans[rhi * 64u + m32] * LOG2E_F);
        EhC[k].x = (_Float16)c0; EhC[k].y = (_Float16)c1; sC += c0 + c1;
        const float d0 = EXP2F(trans[rlo * 64u + cD] * LOG2E_F);
        const float d1 = EXP2F(trans[rhi * 64u + cD] * LOG2E_F);
        EhD[k].x = (_Float16)d0; EhD[k].y = (_Float16)d1; sD += d0 + d1;
    }
    // psum_j = sum_i E[i][j] via the same merge network (h == 1 self-check)
    const float psA  = sA + __uint_as_float(x16(__float_as_uint(sB), s16));
    const float psA2 = sC + __uint_as_float(x16(__float_as_uint(sD), s16));
    const float psum = psA + __uint_as_float(x32(__float_as_uint(psA2), s32));

    // ---- preload obs rows 1..8 (row for step m is m+1, clamped)
    float cur[8];
#pragma unroll
    for (int u = 0; u < 8; ++u) {
        const int row = (u + 1 < T) ? (u + 1) : (T - 1);
        cur[u] = mine ? prow[(size_t)row * L + lane] : 0.f;
    }

    // ---- init (t=1): q = exp2(pred0) * psum; uniform SMALL -> c_base
    int Ci = 0;                              // integer scale accumulator
    const float c_base = SMALLF * LOG2E_F;
    float hf;                                // per-lane h (f32; cvt inside step)
    {
        const float q0 = psum * EXP2F((mine ? prow[lane] : 0.f) * LOG2E_F);
        const float sc = step_scale(q0, Ci);
        hf = q0 * sc;
    }

    // ---- middle steps m = 0..nmid-1 in chunks of 8 (step m uses row m+1)
    const int nfull = nmid >> 3;
    const int rem   = nmid & 7;
    for (int c = 0; c < nfull; ++c) {
        float W[8], nxt[8];
#pragma unroll
        for (int u = 0; u < 8; ++u)
            W[u] = EXP2F(cur[u] * LOG2E_F);      // off the serial chain
        const int base = 8 * (c + 1) + 1;
#pragma unroll
        for (int u = 0; u < 8; ++u) {            // issue next chunk's loads
            const int row = (base + u < T) ? (base + u) : (T - 1);
            nxt[u] = mine ? prow[(size_t)row * L + lane] : 0.f;
        }
#pragma unroll
        for (int u = 0; u < 8; ++u) {
            const float ss = step_ss(hf, EhA, EhB, EhC, EhD, b2, s16, s32);
            const float sc = step_scale(ss, Ci);
            hf = ss * (W[u] * sc);
        }
#pragma unroll
        for (int u = 0; u < 8; ++u) cur[u] = nxt[u];
    }

    // ---- remainder middle steps: cur[u] holds row 8*nfull+1+u
    float Wr[7];
#pragma unroll
    for (int u = 0; u < 7; ++u)
        Wr[u] = EXP2F(cur[u] * LOG2E_F);         // precomputed, off-chain
#pragma unroll
    for (int u = 0; u < 7; ++u) {
        if (u < rem) {
            const float ss = step_ss(hf, EhA, EhB, EhC, EhD, b2, s16, s32);
            const float sc = step_scale(ss, Ci);
            hf = ss * (Wr[u] * sc);
        }
    }

    // ---- final step t = slen+1 in log domain (e_s has +1000)
    {
        const float ssf = step_ss(hf, EhA, EhB, EhC, EhD, b2, s16, s32);
        const float pvf = (slen < T) ? cur[rem] : 0.f;  // pred row slen (or r_pad)
        float ob;
        if (lane < 62)       ob = pvf + SMALLF;  // pred/r_pad + e_s SMALL
        else if (lane == 62) ob = SMALLF;        // SMALL + 0
        else                 ob = 0.f;           // SMALL + 1000
        const float alpha = c_base + (float)Ci + LOG2F(ssf) + ob * LOG2E_F;

        float mx = alpha;
#pragma unroll
        for (int k = 32; k >= 1; k >>= 1)
            mx = fmaxf(mx, __shfl_xor(mx, k, 64));
        float pe = EXP2F(alpha - mx);
#pragma unroll
        for (int k = 32; k >= 1; k >>= 1)
            pe += __shfl_xor(pe, k, 64);
#pragma unroll
        for (int k = 32; k >= 1; k >>= 1)
            gacc += __shfl_xor(gacc, k, 64);

        if (lane == 0) {
            const float logZ2 = mx + LOG2F(pe);  // base-2
            atomicAdd(out, LN2_F * logZ2 - gacc);
        }
    }
}

extern "C" void kernel_launch(void* const* d_in, const int* in_sizes, int n_in,
                              void* d_out, int out_size, void* d_ws, size_t ws_size,
                              hipStream_t stream) {
    const float* pred  = (const float*)d_in[0];
    const int*   ref   = (const int*)  d_in[1];
    const int*   slen  = (const int*)  d_in[2];
    const float* trans = (const float*)d_in[3];

    const int B = in_sizes[2];                 // 1024
    const int T = in_sizes[1] / B;             // 512
    const int L = in_sizes[0] / in_sizes[1];   // 62

    hipMemsetAsync(d_out, 0, sizeof(float), stream);
    crf_fused_kernel<<<B, 64, 0, stream>>>(pred, ref, slen, trans,
                                           (float*)d_out, T, L);
}